// Round 4
// baseline (75.767 us; speedup 1.0000x reference)
//
#include <hip/hip_runtime.h>

// Diagonal depthwise conv, derived from the reference:
//   View x as X[R][W], R = B*C*H = 131072, W = 256.
//   out[r][w] = bias[c] + sum_k weight[c][k] * X[(r+2-k) mod R][w+k-2]
//   where c = (r / H) % C, column OOB -> 0, row index wraps mod R
//   (torch.roll on the fully-flattened tensor wraps across h/c/b).
//
// Vertical-strip version: each thread computes a 4-row x 8-col output tile.
// The 4 rows of a quad share one channel (4 divides 256), so one weight set.
// Stream source rows rq-2 .. rq+5 (8 windows of 12 floats); window j feeds
// output row i at tap k = i - j + 2 when 0 <= k < 5. This cuts L1 traffic
// per output 2.5x vs the row-wise version (taps reuse windows vertically
// inside the thread instead of re-loading per output row).

#define WIDTH 256
#define RTOT  131072            // 8 * 64 * 256
#define NTOT  (RTOT * WIDTH)    // 33,554,432 (fits int)
#define NCH   64
#define KS    5

typedef float f32x4 __attribute__((ext_vector_type(4)));

__global__ __launch_bounds__(256) void diag_dwconv_kernel(
    const float* __restrict__ x,
    const float* __restrict__ wgt,    // [C][1][KS] flat
    const float* __restrict__ bias,   // [C]
    float* __restrict__ out)
{
    int v  = blockIdx.x * blockDim.x + threadIdx.x;  // [0, RTOT/4 * 32)
    int rq = (v >> 5) << 2;          // base output row of the 4-row quad
    int w0 = (v & 31) << 3;          // first output column
    int c  = (rq >> 8) & (NCH - 1);  // all 4 rows share this channel

    float wv[KS];
    #pragma unroll
    for (int k = 0; k < KS; ++k) wv[k] = wgt[c * KS + k];
    float b = bias[c];

    float acc[4][8];
    #pragma unroll
    for (int i = 0; i < 4; ++i)
        #pragma unroll
        for (int jj = 0; jj < 8; ++jj) acc[i][jj] = b;

    bool edgeL = (w0 == 0);
    bool edgeR = (w0 == WIDTH - 8);

    #pragma unroll
    for (int j = -2; j <= 5; ++j) {           // source row rq + j
        int rk = rq + j;
        if (rk < 0)          rk += RTOT;      // wrap across flat tensor
        else if (rk >= RTOT) rk -= RTOT;
        int base = rk * WIDTH + w0;

        int loff = base - 2;                  // OOB only if rk==0 && w0==0
        if (loff < 0) loff = 0;               // loaded value is masked below
        int roff = base + 8;                  // OOB only if rk==RTOT-1 && w0==248
        if (roff > NTOT - 2) roff = NTOT - 2; // loaded value is masked below

        float2 L  = *reinterpret_cast<const float2*>(x + loff);     // w0-2, w0-1
        float4 M1 = *reinterpret_cast<const float4*>(x + base);     // w0 .. w0+3
        float4 M2 = *reinterpret_cast<const float4*>(x + base + 4); // w0+4 .. w0+7
        float2 R  = *reinterpret_cast<const float2*>(x + roff);     // w0+8, w0+9

        if (edgeL) { L.x = 0.f; L.y = 0.f; }  // cols < 0 contribute 0
        if (edgeR) { R.x = 0.f; R.y = 0.f; }  // cols >= WIDTH contribute 0

        float F[12] = { L.x, L.y,
                        M1.x, M1.y, M1.z, M1.w,
                        M2.x, M2.y, M2.z, M2.w,
                        R.x, R.y };

        #pragma unroll
        for (int i = 0; i < 4; ++i) {         // output row rq + i
            int k = i - j + 2;                // tap index (compile-time const)
            if (k >= 0 && k < KS) {
                #pragma unroll
                for (int jj = 0; jj < 8; ++jj)
                    acc[i][jj] = fmaf(wv[k], F[jj + k], acc[i][jj]);
            }
        }
    }

    #pragma unroll
    for (int i = 0; i < 4; ++i) {
        int ob = (rq + i) * WIDTH + w0;
        f32x4 lo = { acc[i][0], acc[i][1], acc[i][2], acc[i][3] };
        f32x4 hi = { acc[i][4], acc[i][5], acc[i][6], acc[i][7] };
        __builtin_nontemporal_store(lo, reinterpret_cast<f32x4*>(out + ob));
        __builtin_nontemporal_store(hi, reinterpret_cast<f32x4*>(out + ob + 4));
    }
}

extern "C" void kernel_launch(void* const* d_in, const int* in_sizes, int n_in,
                              void* d_out, int out_size, void* d_ws, size_t ws_size,
                              hipStream_t stream) {
    const float* x    = (const float*)d_in[0];
    const float* wgt  = (const float*)d_in[1];
    const float* bias = (const float*)d_in[2];
    float* out        = (float*)d_out;

    // one thread per 32 outputs (4 rows x 8 cols): 33,554,432 / 32 = 1,048,576
    int threads = 256;
    int blocks  = (out_size / 32 + threads - 1) / threads;   // 4096
    diag_dwconv_kernel<<<blocks, threads, 0, stream>>>(x, wgt, bias, out);
}

// Round 5
// 59.992 us; speedup vs baseline: 1.2630x; 1.2630x over previous
//
#include <hip/hip_runtime.h>

// Diagonal depthwise conv, derived from the reference:
//   View x as X[R][W], R = B*C*H = 131072, W = 256.
//   out[r][w] = bias[c] + sum_k weight[c][k] * X[(r+2-k) mod R][w+k-2]
//   where c = (r / H) % C, column OOB -> 0, row index wraps mod R
//   (torch.roll on the fully-flattened tensor wraps across h/c/b).
//
// Vertical-strip version: each thread computes a 4-row x 8-col output tile.
// The 4 rows of a quad share one channel (4 divides 256), so one weight set.
// Stream source rows rq-2 .. rq+5 (8 windows of 12 floats); window j feeds
// output row i at tap k = i - j + 2 when 0 <= k < 5.
//
// NOTE (round-3 post-mortem): __builtin_nontemporal_store caused HBM write
// amplification (WRITE_SIZE 131 MB -> 222 MB, +20 us) — nt stores bypass L2
// write coalescing. Regular float4 stores here.

#define WIDTH 256
#define RTOT  131072            // 8 * 64 * 256
#define NTOT  (RTOT * WIDTH)    // 33,554,432 (fits int)
#define NCH   64
#define KS    5

__global__ __launch_bounds__(256) void diag_dwconv_kernel(
    const float* __restrict__ x,
    const float* __restrict__ wgt,    // [C][1][KS] flat
    const float* __restrict__ bias,   // [C]
    float* __restrict__ out)
{
    int v  = blockIdx.x * blockDim.x + threadIdx.x;  // [0, RTOT/4 * 32)
    int rq = (v >> 5) << 2;          // base output row of the 4-row quad
    int w0 = (v & 31) << 3;          // first output column
    int c  = (rq >> 8) & (NCH - 1);  // all 4 rows share this channel

    float wv[KS];
    #pragma unroll
    for (int k = 0; k < KS; ++k) wv[k] = wgt[c * KS + k];
    float b = bias[c];

    float acc[4][8];
    #pragma unroll
    for (int i = 0; i < 4; ++i)
        #pragma unroll
        for (int jj = 0; jj < 8; ++jj) acc[i][jj] = b;

    bool edgeL = (w0 == 0);
    bool edgeR = (w0 == WIDTH - 8);

    #pragma unroll
    for (int j = -2; j <= 5; ++j) {           // source row rq + j
        int rk = rq + j;
        if (rk < 0)          rk += RTOT;      // wrap across flat tensor
        else if (rk >= RTOT) rk -= RTOT;
        int base = rk * WIDTH + w0;

        int loff = base - 2;                  // OOB only if rk==0 && w0==0
        if (loff < 0) loff = 0;               // loaded value is masked below
        int roff = base + 8;                  // OOB only if rk==RTOT-1 && w0==248
        if (roff > NTOT - 2) roff = NTOT - 2; // loaded value is masked below

        float2 L  = *reinterpret_cast<const float2*>(x + loff);     // w0-2, w0-1
        float4 M1 = *reinterpret_cast<const float4*>(x + base);     // w0 .. w0+3
        float4 M2 = *reinterpret_cast<const float4*>(x + base + 4); // w0+4 .. w0+7
        float2 R  = *reinterpret_cast<const float2*>(x + roff);     // w0+8, w0+9

        if (edgeL) { L.x = 0.f; L.y = 0.f; }  // cols < 0 contribute 0
        if (edgeR) { R.x = 0.f; R.y = 0.f; }  // cols >= WIDTH contribute 0

        float F[12] = { L.x, L.y,
                        M1.x, M1.y, M1.z, M1.w,
                        M2.x, M2.y, M2.z, M2.w,
                        R.x, R.y };

        #pragma unroll
        for (int i = 0; i < 4; ++i) {         // output row rq + i
            int k = i - j + 2;                // tap index (compile-time const)
            if (k >= 0 && k < KS) {
                #pragma unroll
                for (int jj = 0; jj < 8; ++jj)
                    acc[i][jj] = fmaf(wv[k], F[jj + k], acc[i][jj]);
            }
        }
    }

    #pragma unroll
    for (int i = 0; i < 4; ++i) {
        int ob = (rq + i) * WIDTH + w0;
        float4 lo = make_float4(acc[i][0], acc[i][1], acc[i][2], acc[i][3]);
        float4 hi = make_float4(acc[i][4], acc[i][5], acc[i][6], acc[i][7]);
        *reinterpret_cast<float4*>(out + ob)     = lo;
        *reinterpret_cast<float4*>(out + ob + 4) = hi;
    }
}

extern "C" void kernel_launch(void* const* d_in, const int* in_sizes, int n_in,
                              void* d_out, int out_size, void* d_ws, size_t ws_size,
                              hipStream_t stream) {
    const float* x    = (const float*)d_in[0];
    const float* wgt  = (const float*)d_in[1];
    const float* bias = (const float*)d_in[2];
    float* out        = (float*)d_out;

    // one thread per 32 outputs (4 rows x 8 cols): 33,554,432 / 32 = 1,048,576
    int threads = 256;
    int blocks  = (out_size / 32 + threads - 1) / threads;   // 4096
    diag_dwconv_kernel<<<blocks, threads, 0, stream>>>(x, wgt, bias, out);
}

// Round 6
// 53.964 us; speedup vs baseline: 1.4040x; 1.1117x over previous
//
#include <hip/hip_runtime.h>

// Diagonal depthwise conv, derived from the reference:
//   View x as X[R][W], R = B*C*H = 131072, W = 256.
//   out[r][w] = bias[c] + sum_k weight[c][k] * X[(r+2-k) mod R][w+k-2]
//   where c = (r / H) % C, column OOB -> 0, row index wraps mod R
//   (torch.roll on the fully-flattened tensor wraps across h/c/b).
//
// Round-5 design: 2 rows x 4 cols per thread.
//  * Stores are ONE float4 per row with consecutive lanes at consecutive
//    16B addresses (w0 = (v&63)*4) -> each store instruction covers a
//    contiguous 1KB per wave -> full 64B HBM bursts even with nt.
//  * nt (nontemporal) stores keep the write stream from allocating in
//    L2/L3, so x (128 MiB) stays resident in the 256 MiB Infinity Cache
//    across graph replays (round-3/4 A/B: FETCH 74 MB w/ nt vs 101 MB
//    cached; round-3's WRITE amplification was the strided store pattern,
//    16B-used-per-32B-stride per instruction, not nt itself).
//  * Wave-uniform rq/c -> weights/bias via scalar loads; edge lanes are
//    lane 0 / lane 63 only.

#define WIDTH 256
#define RTOT  131072            // 8 * 64 * 256
#define NTOT  (RTOT * WIDTH)    // 33,554,432 (fits int)
#define NCH   64
#define KS    5

typedef float f32x4 __attribute__((ext_vector_type(4)));

__global__ __launch_bounds__(256) void diag_dwconv_kernel(
    const float* __restrict__ x,
    const float* __restrict__ wgt,    // [C][1][KS] flat
    const float* __restrict__ bias,   // [C]
    float* __restrict__ out)
{
    int v  = blockIdx.x * blockDim.x + threadIdx.x;  // [0, RTOT/2 * 64)
    int rq = (v >> 6) << 1;          // base output row of the 2-row pair (wave-uniform)
    int w0 = (v & 63) << 2;          // 4-col segment; lanes cover one full row-pair
    int c  = (rq >> 8) & (NCH - 1);  // wave-uniform channel

    float wv[KS];
    #pragma unroll
    for (int k = 0; k < KS; ++k) wv[k] = wgt[c * KS + k];
    float b = bias[c];

    float acc[2][4];
    #pragma unroll
    for (int i = 0; i < 2; ++i)
        #pragma unroll
        for (int jj = 0; jj < 4; ++jj) acc[i][jj] = b;

    bool edgeL = (w0 == 0);           // lane 0 of the wave
    bool edgeR = (w0 == WIDTH - 4);   // lane 63 of the wave

    #pragma unroll
    for (int j = -2; j <= 3; ++j) {           // source row rq + j
        int rk = rq + j;
        if (rk < 0)          rk += RTOT;      // wrap across flat tensor
        else if (rk >= RTOT) rk -= RTOT;
        int base = rk * WIDTH + w0;

        int loff = base - 2;                  // OOB only if rk==0 && w0==0
        if (loff < 0) loff = 0;               // loaded value is masked below
        int roff = base + 4;                  // OOB only if rk==RTOT-1 && w0==252
        if (roff > NTOT - 2) roff = NTOT - 2; // loaded value is masked below

        float2 L = *reinterpret_cast<const float2*>(x + loff);  // w0-2, w0-1
        float4 M = *reinterpret_cast<const float4*>(x + base);  // w0 .. w0+3
        float2 R = *reinterpret_cast<const float2*>(x + roff);  // w0+4, w0+5

        if (edgeL) { L.x = 0.f; L.y = 0.f; }  // cols < 0 contribute 0
        if (edgeR) { R.x = 0.f; R.y = 0.f; }  // cols >= WIDTH contribute 0

        float F[8] = { L.x, L.y, M.x, M.y, M.z, M.w, R.x, R.y };

        #pragma unroll
        for (int i = 0; i < 2; ++i) {         // output row rq + i
            int k = i - j + 2;                // tap index (compile-time const)
            if (k >= 0 && k < KS) {
                #pragma unroll
                for (int jj = 0; jj < 4; ++jj)
                    acc[i][jj] = fmaf(wv[k], F[jj + k], acc[i][jj]);
            }
        }
    }

    #pragma unroll
    for (int i = 0; i < 2; ++i) {
        int ob = (rq + i) * WIDTH + w0;
        f32x4 o = { acc[i][0], acc[i][1], acc[i][2], acc[i][3] };
        __builtin_nontemporal_store(o, reinterpret_cast<f32x4*>(out + ob));
    }
}

extern "C" void kernel_launch(void* const* d_in, const int* in_sizes, int n_in,
                              void* d_out, int out_size, void* d_ws, size_t ws_size,
                              hipStream_t stream) {
    const float* x    = (const float*)d_in[0];
    const float* wgt  = (const float*)d_in[1];
    const float* bias = (const float*)d_in[2];
    float* out        = (float*)d_out;

    // one thread per 8 outputs (2 rows x 4 cols): 33,554,432 / 8 = 4,194,304
    int threads = 256;
    int blocks  = (out_size / 8 + threads - 1) / threads;   // 16384
    diag_dwconv_kernel<<<blocks, threads, 0, stream>>>(x, wgt, bias, out);
}

// Round 7
// 47.550 us; speedup vs baseline: 1.5934x; 1.1349x over previous
//
#include <hip/hip_runtime.h>

// Diagonal depthwise conv, derived from the reference:
//   View x as X[R][W], R = B*C*H = 131072, W = 256.
//   out[r][w] = bias[c] + sum_k weight[c][k] * X[(r+2-k) mod R][w+k-2]
//   where c = (r / H) % C, column OOB -> 0, row index wraps mod R
//   (torch.roll on the fully-flattened tensor wraps across h/c/b).
//
// Round-6 design (4 rows x 4 cols per thread):
//  * w0 = (lane)*4 -> each store instruction is one float4 per lane at
//    consecutive addresses = dense 1KB/wave bursts; nt stores keep the
//    write stream out of L2/L3 so x stays Infinity-Cache resident
//    (round-3/4/5 A/B established both effects).
//  * 8 source rows (rq-2..rq+5) x (float2+float4+float2) aligned window
//    loads feed 16 outputs: 1.5 load-insts/output vs 2.25 in round 5.
//    All 24 loads are independent -> deep MLP per wave (latency-bound fix).
//  * channel is wave-uniform: readfirstlane -> weights/bias via s_load.

#define WIDTH 256
#define RTOT  131072            // 8 * 64 * 256
#define NTOT  (RTOT * WIDTH)    // 33,554,432 (fits int)
#define NCH   64
#define KS    5

typedef float f32x4 __attribute__((ext_vector_type(4)));

__global__ __launch_bounds__(256) void diag_dwconv_kernel(
    const float* __restrict__ x,
    const float* __restrict__ wgt,    // [C][1][KS] flat
    const float* __restrict__ bias,   // [C]
    float* __restrict__ out)
{
    int v  = blockIdx.x * blockDim.x + threadIdx.x;  // [0, RTOT/4 * 64)
    int rq = (v >> 6) << 2;          // base output row of the 4-row quad (wave-uniform)
    int w0 = (v & 63) << 2;          // 4-col segment; lanes cover one full row
    int c  = __builtin_amdgcn_readfirstlane((rq >> 8) & (NCH - 1));

    float wv[KS];
    #pragma unroll
    for (int k = 0; k < KS; ++k) wv[k] = wgt[c * KS + k];   // scalar loads
    float b = bias[c];

    float acc[4][4];
    #pragma unroll
    for (int i = 0; i < 4; ++i)
        #pragma unroll
        for (int jj = 0; jj < 4; ++jj) acc[i][jj] = b;

    bool edgeL = (w0 == 0);           // lane 0 of the wave
    bool edgeR = (w0 == WIDTH - 4);   // lane 63 of the wave

    #pragma unroll
    for (int j = -2; j <= 5; ++j) {           // source row rq + j
        int rk = rq + j;
        if (rk < 0)          rk += RTOT;      // wrap across flat tensor
        else if (rk >= RTOT) rk -= RTOT;
        int base = rk * WIDTH + w0;

        int loff = base - 2;                  // OOB only if rk==0 && w0==0
        if (loff < 0) loff = 0;               // loaded value is masked below
        int roff = base + 4;                  // OOB only if rk==RTOT-1 && w0==252
        if (roff > NTOT - 2) roff = NTOT - 2; // loaded value is masked below

        float2 L = *reinterpret_cast<const float2*>(x + loff);  // w0-2, w0-1
        float4 M = *reinterpret_cast<const float4*>(x + base);  // w0 .. w0+3
        float2 R = *reinterpret_cast<const float2*>(x + roff);  // w0+4, w0+5

        if (edgeL) { L.x = 0.f; L.y = 0.f; }  // cols < 0 contribute 0
        if (edgeR) { R.x = 0.f; R.y = 0.f; }  // cols >= WIDTH contribute 0

        float F[8] = { L.x, L.y, M.x, M.y, M.z, M.w, R.x, R.y };

        #pragma unroll
        for (int i = 0; i < 4; ++i) {         // output row rq + i
            int k = i - j + 2;                // tap index (compile-time const)
            if (k >= 0 && k < KS) {
                #pragma unroll
                for (int jj = 0; jj < 4; ++jj)
                    acc[i][jj] = fmaf(wv[k], F[jj + k], acc[i][jj]);
            }
        }
    }

    #pragma unroll
    for (int i = 0; i < 4; ++i) {
        int ob = (rq + i) * WIDTH + w0;
        f32x4 o = { acc[i][0], acc[i][1], acc[i][2], acc[i][3] };
        __builtin_nontemporal_store(o, reinterpret_cast<f32x4*>(out + ob));
    }
}

extern "C" void kernel_launch(void* const* d_in, const int* in_sizes, int n_in,
                              void* d_out, int out_size, void* d_ws, size_t ws_size,
                              hipStream_t stream) {
    const float* x    = (const float*)d_in[0];
    const float* wgt  = (const float*)d_in[1];
    const float* bias = (const float*)d_in[2];
    float* out        = (float*)d_out;

    // one thread per 16 outputs (4 rows x 4 cols): 33,554,432 / 16 = 2,097,152
    int threads = 256;
    int blocks  = (out_size / 16 + threads - 1) / threads;   // 8192
    diag_dwconv_kernel<<<blocks, threads, 0, stream>>>(x, wgt, bias, out);
}